// Round 1
// baseline (2655.589 us; speedup 1.0000x reference)
//
#include <hip/hip_runtime.h>
#include <hip/hip_bf16.h>

#define BB 32
#define CC 320
#define HH 64
#define WW 64
#define CTX 1024
#define ROI 9
#define SS 81
#define CK 256

// workspace layout (float offsets)
#define N_XG   (BB*CC*SS)            // 829440
#define OFF_XG   0
#define OFF_KMAP (OFF_XG + N_XG)               // 829440
#define N_KMAP (BB*CK*CTX)                     // 8388608
#define OFF_CTXT (OFF_KMAP + N_KMAP)           // 9218048
#define N_CTXT (BB*CTX*CK)                     // 8388608
#define OFF_V  (OFF_CTXT + N_CTXT)             // 17606656
#define N_V    (BB*CK*CC)                      // 2621440
#define OFF_K  (OFF_V + N_V)                   // 20228096
#define OFF_Q  (OFF_K + N_V)                   // 22849536
#define OFF_XO (OFF_Q + N_XG)                  // 23678976

#define KC 16
#define ASTR 36
#define BSTR 260

__device__ __forceinline__ float block_reduce_sum(float v, float* red) {
    #pragma unroll
    for (int off = 32; off > 0; off >>= 1) v += __shfl_down(v, off, 64);
    int wid = threadIdx.x >> 6;
    __syncthreads();                       // protect red from previous use
    if ((threadIdx.x & 63) == 0) red[wid] = v;
    __syncthreads();
    return red[0] + red[1] + red[2] + red[3];
}

// ---------------- ROI align + GroupNorm -> xg (B,320,81) ----------------
__global__ __launch_bounds__(256) void roi_gn_kernel(
    const float* __restrict__ gx, const float* __restrict__ bbox,
    const float* __restrict__ ln_g, const float* __restrict__ ln_b,
    float* __restrict__ xg) {
    int b = blockIdx.x, g = blockIdx.y;
    int tid = threadIdx.x;
    __shared__ float vals[810];
    __shared__ int iy0[ROI], iy1[ROI], ix0[ROI], ix1[ROI];
    __shared__ float fly[ROI], flx[ROI];
    __shared__ float red[4];
    if (tid < ROI) {
        float x1 = bbox[b*4+0], y1 = bbox[b*4+1], x2 = bbox[b*4+2], y2 = bbox[b*4+3];
        float rw = fmaxf(x2 - x1, 1.0f), rh = fmaxf(y2 - y1, 1.0f);
        float gp = (float)tid + 0.5f;
        float yv = y1 + gp * (rh * (1.0f/ROI));
        float xv = x1 + gp * (rw * (1.0f/ROI));
        yv = fminf(fmaxf(yv, 0.0f), (float)(HH-1));
        xv = fminf(fmaxf(xv, 0.0f), (float)(WW-1));
        float y0f = floorf(yv), x0f = floorf(xv);
        iy0[tid] = (int)y0f; iy1[tid] = min((int)y0f + 1, HH-1);
        ix0[tid] = (int)x0f; ix1[tid] = min((int)x0f + 1, WW-1);
        fly[tid] = yv - y0f; flx[tid] = xv - x0f;
    }
    __syncthreads();
    const float* img = gx + ((size_t)b*CC + g*10) * (HH*WW);
    float psum = 0.0f;
    for (int e = tid; e < 810; e += 256) {
        int cl = e / SS; int s = e - cl*SS; int i = s / ROI; int j = s - i*ROI;
        const float* im = img + (size_t)cl * (HH*WW);
        float ly = fly[i], lx = flx[j];
        float v00 = im[iy0[i]*WW + ix0[j]];
        float v01 = im[iy0[i]*WW + ix1[j]];
        float v10 = im[iy1[i]*WW + ix0[j]];
        float v11 = im[iy1[i]*WW + ix1[j]];
        float v = v00*(1.0f-ly)*(1.0f-lx) + v01*(1.0f-ly)*lx
                + v10*ly*(1.0f-lx)        + v11*ly*lx;
        vals[e] = v;
        psum += v;
    }
    float mean = block_reduce_sum(psum, red) * (1.0f/810.0f);
    float pvar = 0.0f;
    for (int e = tid; e < 810; e += 256) { float d = vals[e] - mean; pvar += d*d; }
    float var = block_reduce_sum(pvar, red) * (1.0f/810.0f);
    float rs = rsqrtf(var + 1e-6f);
    for (int e = tid; e < 810; e += 256) {
        int cl = e / SS; int s = e - cl*SS;
        int c = g*10 + cl;
        xg[((size_t)b*CC + c)*SS + s] = (vals[e] - mean) * rs * ln_g[c] + ln_b[c];
    }
}

// ---------------- context GroupNorm -> kmap (B,256,1024) [p][ch] ----------------
__global__ __launch_bounds__(256) void ctx_gn_kernel(
    const float* __restrict__ ctx, const float* __restrict__ cn_g,
    const float* __restrict__ cn_b, float* __restrict__ kmap) {
    int b = blockIdx.x, g = blockIdx.y;
    int tid = threadIdx.x;
    __shared__ float red[4];
    int ch = g*32 + (tid & 31);
    int p0 = tid >> 5;  // 0..7
    float vals[32];
    float psum = 0.0f;
    const float* base = ctx + (size_t)b*CK*CTX + ch;
    #pragma unroll
    for (int i = 0; i < 32; ++i) {
        int p = p0 + (i << 3);
        vals[i] = base[(size_t)p << 10];
        psum += vals[i];
    }
    float mean = block_reduce_sum(psum, red) * (1.0f/8192.0f);
    float pvar = 0.0f;
    #pragma unroll
    for (int i = 0; i < 32; ++i) { float d = vals[i] - mean; pvar += d*d; }
    float var = block_reduce_sum(pvar, red) * (1.0f/8192.0f);
    float rs = rsqrtf(var + 1e-6f);
    float gam = cn_g[ch] * rs, bet = cn_b[ch];
    float* ob = kmap + (size_t)b*CK*CTX + ch;
    #pragma unroll
    for (int i = 0; i < 32; ++i) {
        int p = p0 + (i << 3);
        ob[(size_t)p << 10] = (vals[i] - mean) * gam + bet;
    }
}

// ---------------- context transpose -> ctx_t (B,1024,256) [ch][p] ----------------
__global__ __launch_bounds__(256) void ctx_tr_kernel(
    const float* __restrict__ ctx, float* __restrict__ ctx_t) {
    int b = blockIdx.x, g = blockIdx.y;  // 32-ch tile
    int tid = threadIdx.x;
    __shared__ float tile[32][257];
    int chl = tid & 31, p0 = tid >> 5;
    const float* base = ctx + (size_t)b*CK*CTX + g*32 + chl;
    #pragma unroll
    for (int i = 0; i < 32; ++i) {
        int p = p0 + (i << 3);
        tile[chl][p] = base[(size_t)p << 10];
    }
    __syncthreads();
    for (int e = tid; e < 8192; e += 256) {
        int c2 = e >> 8, p = e & 255;
        ctx_t[((size_t)b*CTX + g*32 + c2)*CK + p] = tile[c2][p];
    }
}

// ---------------- GEMM compute core (shared shape) ----------------
#define GEMM_DECL \
    int tid = threadIdx.x; \
    int to = tid >> 5, tp = tid & 31; \
    int ka = tid & 15, ma = (tid >> 4) << 1; \
    __shared__ __align__(16) float As[KC*ASTR]; \
    __shared__ __align__(16) float Bs[KC*BSTR]; \
    float acc[4][8]; \
    _Pragma("unroll") for (int r = 0; r < 4; ++r) \
        _Pragma("unroll") for (int c = 0; c < 8; ++c) acc[r][c] = 0.0f;

#define GEMM_COMPUTE \
    _Pragma("unroll") \
    for (int kk = 0; kk < KC; ++kk) { \
        float a4[4], b8[8]; \
        *(float4*)a4     = *(const float4*)&As[kk*ASTR + (to<<2)]; \
        *(float4*)&b8[0] = *(const float4*)&Bs[kk*BSTR + (tp<<3)]; \
        *(float4*)&b8[4] = *(const float4*)&Bs[kk*BSTR + (tp<<3) + 4]; \
        _Pragma("unroll") for (int r = 0; r < 4; ++r) \
            _Pragma("unroll") for (int c = 0; c < 8; ++c) \
                acc[r][c] += a4[r] * b8[c]; \
    }

// ---------------- q projection: q_t (B,81,320) [s][o] ----------------
__global__ __launch_bounds__(256) void qproj_kernel(
    const float* __restrict__ xg, const float* __restrict__ w_in,
    const float* __restrict__ b_in, const float* __restrict__ ind,
    float* __restrict__ q_t) {
    int b = blockIdx.x, ot = blockIdx.y;
    GEMM_DECL
    int mbase = ot * 32;
    for (int k0 = 0; k0 < CC; k0 += KC) {
        __syncthreads();
        As[ka*ASTR + ma]     = w_in[(size_t)(mbase+ma)  *(CC+2) + k0 + ka];
        As[ka*ASTR + ma + 1] = w_in[(size_t)(mbase+ma+1)*(CC+2) + k0 + ka];
        #pragma unroll
        for (int kk = 0; kk < KC; ++kk) {
            float v = 0.0f;
            if (tid < SS) v = xg[((size_t)b*CC + k0 + kk)*SS + tid];
            Bs[kk*BSTR + tid] = v;
        }
        __syncthreads();
        GEMM_COMPUTE
    }
    int m0 = mbase + (to << 2);
    float i0 = ind[b*2+0], i1 = ind[b*2+1];
    float bias[4];
    #pragma unroll
    for (int r = 0; r < 4; ++r)
        bias[r] = b_in[m0+r] + w_in[(size_t)(m0+r)*(CC+2) + CC]*i0
                             + w_in[(size_t)(m0+r)*(CC+2) + CC+1]*i1;
    #pragma unroll
    for (int c = 0; c < 8; ++c) {
        int n = (tp << 3) + c;
        if (n < SS) {
            float4 o = make_float4(acc[0][c]+bias[0], acc[1][c]+bias[1],
                                   acc[2][c]+bias[2], acc[3][c]+bias[3]);
            *(float4*)&q_t[((size_t)b*SS + n)*CC + m0] = o;
        }
    }
}

// ---------------- k projection: k_t (B,256,320) [j][o] ----------------
__global__ __launch_bounds__(256) void kproj_kernel(
    const float* __restrict__ kmap, const float* __restrict__ w_ctx,
    const float* __restrict__ b_ctx, float* __restrict__ k_t) {
    int b = blockIdx.x, ot = blockIdx.y;
    GEMM_DECL
    int mbase = ot * 32;
    int j0 = tid >> 4;
    for (int k0 = 0; k0 < CTX; k0 += KC) {
        __syncthreads();
        As[ka*ASTR + ma]     = w_ctx[(size_t)(mbase+ma)  *CTX + k0 + ka];
        As[ka*ASTR + ma + 1] = w_ctx[(size_t)(mbase+ma+1)*CTX + k0 + ka];
        #pragma unroll
        for (int i = 0; i < 16; ++i) {
            int j = j0 + (i << 4);
            Bs[ka*BSTR + j] = kmap[((size_t)b*CK + j)*CTX + k0 + ka];
        }
        __syncthreads();
        GEMM_COMPUTE
    }
    int m0 = mbase + (to << 2);
    float bias[4] = {b_ctx[m0], b_ctx[m0+1], b_ctx[m0+2], b_ctx[m0+3]};
    #pragma unroll
    for (int c = 0; c < 8; ++c) {
        int n = (tp << 3) + c;
        float4 o = make_float4(acc[0][c]+bias[0], acc[1][c]+bias[1],
                               acc[2][c]+bias[2], acc[3][c]+bias[3]);
        *(float4*)&k_t[((size_t)b*CK + n)*CC + m0] = o;
    }
}

// ---------------- conv 3x3 SAME: v_t (B,256,320) [p][o] ----------------
__global__ __launch_bounds__(256) void conv3_kernel(
    const float* __restrict__ ctx_t, const float* __restrict__ w_out,
    const float* __restrict__ b_out, float* __restrict__ v_t) {
    int b = blockIdx.x, ot = blockIdx.y;
    GEMM_DECL
    int mbase = ot * 32;
    int p = tid, py = p >> 4, px = p & 15;
    const float* cbase = ctx_t + (size_t)b*CTX*CK;
    for (int k0 = 0; k0 < 9216; k0 += KC) {
        __syncthreads();
        As[ka*ASTR + ma]     = w_out[(size_t)(mbase+ma)  *9216 + k0 + ka];
        As[ka*ASTR + ma + 1] = w_out[(size_t)(mbase+ma+1)*9216 + k0 + ka];
        #pragma unroll
        for (int kk = 0; kk < KC; ++kk) {
            int k = k0 + kk;
            int ch = k / 9;
            int tap = k - ch*9;
            int dy = tap / 3, dx = tap - dy*3;
            int iy = py + dy - 1, ix = px + dx - 1;
            float v = 0.0f;
            if (iy >= 0 && iy < 16 && ix >= 0 && ix < 16)
                v = cbase[(size_t)ch*CK + iy*16 + ix];
            Bs[kk*BSTR + p] = v;
        }
        __syncthreads();
        GEMM_COMPUTE
    }
    int m0 = mbase + (to << 2);
    float bias[4] = {b_out[m0], b_out[m0+1], b_out[m0+2], b_out[m0+3]};
    #pragma unroll
    for (int c = 0; c < 8; ++c) {
        int n = (tp << 3) + c;
        float4 o = make_float4(acc[0][c]+bias[0], acc[1][c]+bias[1],
                               acc[2][c]+bias[2], acc[3][c]+bias[3]);
        *(float4*)&v_t[((size_t)b*CK + n)*CC + m0] = o;
    }
}

// ---------------- sim + softmax -> attn (B,81,256) in d_out ----------------
__global__ __launch_bounds__(256) void simsoft_kernel(
    const float* __restrict__ q_t, const float* __restrict__ k_t,
    float* __restrict__ attn) {
    int b = blockIdx.x, mt = blockIdx.y;  // mt<3
    GEMM_DECL
    int mbase = mt * 32;
    int j0 = tid >> 4;
    for (int k0 = 0; k0 < CC; k0 += KC) {
        __syncthreads();
        int mg = mbase + ma;
        As[ka*ASTR + ma]     = (mg   < SS) ? q_t[((size_t)b*SS + mg  )*CC + k0 + ka] : 0.0f;
        As[ka*ASTR + ma + 1] = (mg+1 < SS) ? q_t[((size_t)b*SS + mg+1)*CC + k0 + ka] : 0.0f;
        #pragma unroll
        for (int i = 0; i < 16; ++i) {
            int j = j0 + (i << 4);
            Bs[ka*BSTR + j] = k_t[((size_t)b*CK + j)*CC + k0 + ka];
        }
        __syncthreads();
        GEMM_COMPUTE
    }
    // softmax over full rows (32 threads sharing `to` hold one row's 256 cols)
    #pragma unroll
    for (int r = 0; r < 4; ++r) {
        float mx = acc[r][0];
        #pragma unroll
        for (int c = 1; c < 8; ++c) mx = fmaxf(mx, acc[r][c]);
        #pragma unroll
        for (int sh = 16; sh > 0; sh >>= 1) mx = fmaxf(mx, __shfl_xor(mx, sh, 64));
        float ex[8]; float s = 0.0f;
        #pragma unroll
        for (int c = 0; c < 8; ++c) { ex[c] = __expf(acc[r][c] - mx); s += ex[c]; }
        #pragma unroll
        for (int sh = 16; sh > 0; sh >>= 1) s += __shfl_xor(s, sh, 64);
        float inv = 1.0f / s;
        #pragma unroll
        for (int c = 0; c < 8; ++c) acc[r][c] = ex[c] * inv;
    }
    int m0 = mbase + (to << 2);
    #pragma unroll
    for (int r = 0; r < 4; ++r) {
        int m = m0 + r;
        if (m < SS) {
            float* dst = &attn[((size_t)b*SS + m)*CK + (tp << 3)];
            *(float4*)dst       = make_float4(acc[r][0], acc[r][1], acc[r][2], acc[r][3]);
            *(float4*)(dst + 4) = make_float4(acc[r][4], acc[r][5], acc[r][6], acc[r][7]);
        }
    }
}

// ---------------- xo = attn @ v : xo_t (B,81,320) [s][c] ----------------
__global__ __launch_bounds__(256) void xogemm_kernel(
    const float* __restrict__ attn, const float* __restrict__ v_t,
    float* __restrict__ xo_t) {
    int b = blockIdx.x, mt = blockIdx.y, nt = blockIdx.z;  // mt<3, nt<2
    GEMM_DECL
    int mbase = mt * 32, nbase = nt * 256;
    for (int k0 = 0; k0 < CK; k0 += KC) {
        __syncthreads();
        int mg = mbase + ma;
        As[ka*ASTR + ma]     = (mg   < SS) ? attn[((size_t)b*SS + mg  )*CK + k0 + ka] : 0.0f;
        As[ka*ASTR + ma + 1] = (mg+1 < SS) ? attn[((size_t)b*SS + mg+1)*CK + k0 + ka] : 0.0f;
        #pragma unroll
        for (int kk = 0; kk < KC; ++kk) {
            int n = nbase + tid;
            Bs[kk*BSTR + tid] = (n < CC) ? v_t[((size_t)b*CK + k0 + kk)*CC + n] : 0.0f;
        }
        __syncthreads();
        GEMM_COMPUTE
    }
    int m0 = mbase + (to << 2);
    int n0 = nbase + (tp << 3);
    if (n0 + 8 <= CC) {
        #pragma unroll
        for (int r = 0; r < 4; ++r) {
            int m = m0 + r;
            if (m < SS) {
                float* dst = &xo_t[((size_t)b*SS + m)*CC + n0];
                *(float4*)dst       = make_float4(acc[r][0], acc[r][1], acc[r][2], acc[r][3]);
                *(float4*)(dst + 4) = make_float4(acc[r][4], acc[r][5], acc[r][6], acc[r][7]);
            }
        }
    }
}

// ---------------- paste back: out = global_x + masked gather ----------------
__global__ __launch_bounds__(256) void paste_kernel(
    const float* __restrict__ gx, const float* __restrict__ bbox,
    const float* __restrict__ xo_t, float* __restrict__ out) {
    int idx = blockIdx.x * 256 + threadIdx.x;
    int pix = idx & 4095;
    int bc = idx >> 12;
    int c = bc % CC;
    int b = bc / CC;
    int y = pix >> 6, x = pix & 63;
    float g = gx[idx];
    int bx1 = (int)(bbox[b*4+0] * (float)HH);
    int by1 = (int)(bbox[b*4+1] * (float)HH);
    int bx2 = max((int)(bbox[b*4+2] * (float)HH), bx1 + 1);
    int by2 = max((int)(bbox[b*4+3] * (float)HH), by1 + 1);
    float add = 0.0f;
    if (y >= by1 && y < by2 && x >= bx1 && x < bx2) {
        int sy = min(max((y - by1) * ROI / (by2 - by1), 0), ROI - 1);
        int sx = min(max((x - bx1) * ROI / (bx2 - bx1), 0), ROI - 1);
        add = xo_t[((size_t)b*SS + sy*ROI + sx)*CC + c];
    }
    out[idx] = g + add;
}

extern "C" void kernel_launch(void* const* d_in, const int* in_sizes, int n_in,
                              void* d_out, int out_size, void* d_ws, size_t ws_size,
                              hipStream_t stream) {
    const float* global_x = (const float*)d_in[0];
    const float* context  = (const float*)d_in[1];
    const float* indicator= (const float*)d_in[2];
    const float* bbox     = (const float*)d_in[3];
    const float* ln_g     = (const float*)d_in[4];
    const float* ln_b     = (const float*)d_in[5];
    const float* cn_g     = (const float*)d_in[6];
    const float* cn_b     = (const float*)d_in[7];
    const float* w_in     = (const float*)d_in[8];
    const float* b_in     = (const float*)d_in[9];
    const float* w_ctx    = (const float*)d_in[10];
    const float* b_ctx    = (const float*)d_in[11];
    const float* w_out    = (const float*)d_in[12];
    const float* b_out    = (const float*)d_in[13];

    float* ws   = (float*)d_ws;
    float* xg   = ws + OFF_XG;
    float* kmap = ws + OFF_KMAP;
    float* ctxt = ws + OFF_CTXT;
    float* v_t  = ws + OFF_V;
    float* k_t  = ws + OFF_K;
    float* q_t  = ws + OFF_Q;
    float* xo_t = ws + OFF_XO;

    float* out  = (float*)d_out;                       // (B,320,64,64)
    float* attn = out + (size_t)BB*CC*HH*WW;           // (B,81,256)

    roi_gn_kernel <<<dim3(BB, 32), 256, 0, stream>>>(global_x, bbox, ln_g, ln_b, xg);
    ctx_gn_kernel <<<dim3(BB, 32), 256, 0, stream>>>(context, cn_g, cn_b, kmap);
    ctx_tr_kernel <<<dim3(BB, 32), 256, 0, stream>>>(context, ctxt);
    qproj_kernel  <<<dim3(BB, 10), 256, 0, stream>>>(xg, w_in, b_in, indicator, q_t);
    kproj_kernel  <<<dim3(BB, 10), 256, 0, stream>>>(kmap, w_ctx, b_ctx, k_t);
    conv3_kernel  <<<dim3(BB, 10), 256, 0, stream>>>(ctxt, w_out, b_out, v_t);
    simsoft_kernel<<<dim3(BB, 3),  256, 0, stream>>>(q_t, k_t, attn);
    xogemm_kernel <<<dim3(BB, 3, 2), 256, 0, stream>>>(attn, v_t, xo_t);
    paste_kernel  <<<dim3((BB*CC*HH*WW)/256), 256, 0, stream>>>(global_x, bbox, xo_t, out);
}

// Round 3
// 761.267 us; speedup vs baseline: 3.4884x; 3.4884x over previous
//
#include <hip/hip_runtime.h>
#include <hip/hip_bf16.h>

#define BB 32
#define CC 320
#define HH 64
#define WW 64
#define CTX 1024
#define ROI 9
#define SS 81
#define CK 256

// ---------------- workspace layout (float offsets) ----------------
#define N_XG   (BB*CC*SS)                       // 829440
#define OFF_XG    0
#define NF_CBF    (BB*CK*CTX/2)                 // 4194304 floats (8388608 ushort)
#define OFF_CBFH  (OFF_XG + N_XG)
#define OFF_CBFL  (OFF_CBFH + NF_CBF)
#define OFF_KBFH  (OFF_CBFL + NF_CBF)
#define OFF_KBFL  (OFF_KBFH + NF_CBF)
#define NF_WC     (9*CC*CTX/2)                  // 1474560
#define OFF_WCH   (OFF_KBFL + NF_CBF)
#define OFF_WCL   (OFF_WCH + NF_WC)
#define NF_WK     (CC*CTX/2)                    // 163840
#define OFF_WKH   (OFF_WCL + NF_WC)
#define OFF_WKL   (OFF_WKH + NF_WK)
#define N_V       (BB*CK*CC)                    // 2621440
#define OFF_VPART (OFF_WKL + NF_WK)
#define OFF_V     (OFF_VPART + 4*N_V)
#define OFF_K     (OFF_V + N_V)
#define OFF_Q     (OFF_K + N_V)
#define OFF_XO    (OFF_Q + N_XG)

typedef __attribute__((ext_vector_type(8))) short bf16x8;
typedef __attribute__((ext_vector_type(4))) float f32x4;

__device__ __forceinline__ void split_bf16(float v, ushort& h, ushort& l) {
    __hip_bfloat16 hb = __float2bfloat16(v);
    float hf = __bfloat162float(hb);
    __hip_bfloat16 lb = __float2bfloat16(v - hf);
    union { __hip_bfloat16 b; ushort u; } cu;
    cu.b = hb; h = cu.u;
    cu.b = lb; l = cu.u;
}

__device__ __forceinline__ float block_reduce_sum(float v, float* red) {
    #pragma unroll
    for (int off = 32; off > 0; off >>= 1) v += __shfl_down(v, off, 64);
    int wid = threadIdx.x >> 6;
    __syncthreads();
    if ((threadIdx.x & 63) == 0) red[wid] = v;
    __syncthreads();
    return red[0] + red[1] + red[2] + red[3];
}

// ---------------- ROI align + GroupNorm -> xg (B,320,81) ----------------
__global__ __launch_bounds__(256) void roi_gn_kernel(
    const float* __restrict__ gx, const float* __restrict__ bbox,
    const float* __restrict__ ln_g, const float* __restrict__ ln_b,
    float* __restrict__ xg) {
    int b = blockIdx.x, g = blockIdx.y;
    int tid = threadIdx.x;
    __shared__ float vals[810];
    __shared__ int iy0[ROI], iy1[ROI], ix0[ROI], ix1[ROI];
    __shared__ float fly[ROI], flx[ROI];
    __shared__ float red[4];
    if (tid < ROI) {
        float x1 = bbox[b*4+0], y1 = bbox[b*4+1], x2 = bbox[b*4+2], y2 = bbox[b*4+3];
        float rw = fmaxf(x2 - x1, 1.0f), rh = fmaxf(y2 - y1, 1.0f);
        float gp = (float)tid + 0.5f;
        float yv = y1 + gp * (rh * (1.0f/ROI));
        float xv = x1 + gp * (rw * (1.0f/ROI));
        yv = fminf(fmaxf(yv, 0.0f), (float)(HH-1));
        xv = fminf(fmaxf(xv, 0.0f), (float)(WW-1));
        float y0f = floorf(yv), x0f = floorf(xv);
        iy0[tid] = (int)y0f; iy1[tid] = min((int)y0f + 1, HH-1);
        ix0[tid] = (int)x0f; ix1[tid] = min((int)x0f + 1, WW-1);
        fly[tid] = yv - y0f; flx[tid] = xv - x0f;
    }
    __syncthreads();
    const float* img = gx + ((size_t)b*CC + g*10) * (HH*WW);
    float psum = 0.0f;
    for (int e = tid; e < 810; e += 256) {
        int cl = e / SS; int s = e - cl*SS; int i = s / ROI; int j = s - i*ROI;
        const float* im = img + (size_t)cl * (HH*WW);
        float ly = fly[i], lx = flx[j];
        float v00 = im[iy0[i]*WW + ix0[j]];
        float v01 = im[iy0[i]*WW + ix1[j]];
        float v10 = im[iy1[i]*WW + ix0[j]];
        float v11 = im[iy1[i]*WW + ix1[j]];
        float v = v00*(1.0f-ly)*(1.0f-lx) + v01*(1.0f-ly)*lx
                + v10*ly*(1.0f-lx)        + v11*ly*lx;
        vals[e] = v;
        psum += v;
    }
    float mean = block_reduce_sum(psum, red) * (1.0f/810.0f);
    float pvar = 0.0f;
    for (int e = tid; e < 810; e += 256) { float d = vals[e] - mean; pvar += d*d; }
    float var = block_reduce_sum(pvar, red) * (1.0f/810.0f);
    float rs = rsqrtf(var + 1e-6f);
    for (int e = tid; e < 810; e += 256) {
        int cl = e / SS; int s = e - cl*SS;
        int c = g*10 + cl;
        xg[((size_t)b*CC + c)*SS + s] = (vals[e] - mean) * rs * ln_g[c] + ln_b[c];
    }
}

// ------- context GroupNorm -> kbf hi/lo (B,256,1024) bf16 [b][p][ch] -------
__global__ __launch_bounds__(256) void ctx_gn_kernel(
    const float* __restrict__ ctx, const float* __restrict__ cn_g,
    const float* __restrict__ cn_b, ushort* __restrict__ khi,
    ushort* __restrict__ klo) {
    int b = blockIdx.x, g = blockIdx.y;
    int tid = threadIdx.x;
    __shared__ float red[4];
    int ch = g*32 + (tid & 31);
    int p0 = tid >> 5;  // 0..7
    float vals[32];
    float psum = 0.0f;
    const float* base = ctx + (size_t)b*CK*CTX + ch;
    #pragma unroll
    for (int i = 0; i < 32; ++i) {
        int p = p0 + (i << 3);
        vals[i] = base[(size_t)p << 10];
        psum += vals[i];
    }
    float mean = block_reduce_sum(psum, red) * (1.0f/8192.0f);
    float pvar = 0.0f;
    #pragma unroll
    for (int i = 0; i < 32; ++i) { float d = vals[i] - mean; pvar += d*d; }
    float var = block_reduce_sum(pvar, red) * (1.0f/8192.0f);
    float rs = rsqrtf(var + 1e-6f);
    float gam = cn_g[ch] * rs, bet = cn_b[ch];
    size_t ob = (size_t)b*CK*CTX + ch;
    #pragma unroll
    for (int i = 0; i < 32; ++i) {
        int p = p0 + (i << 3);
        float o = (vals[i] - mean) * gam + bet;
        ushort h, l;
        split_bf16(o, h, l);
        khi[ob + ((size_t)p << 10)] = h;
        klo[ob + ((size_t)p << 10)] = l;
    }
}

// ---------------- split context -> cbf hi/lo ----------------
__global__ __launch_bounds__(256) void split_ctx_kernel(
    const float* __restrict__ src, ushort* __restrict__ hi, ushort* __restrict__ lo) {
    int i = (blockIdx.x*256 + threadIdx.x)*4;
    float4 v = *(const float4*)&src[i];
    ushort4 h, l;
    split_bf16(v.x, h.x, l.x); split_bf16(v.y, h.y, l.y);
    split_bf16(v.z, h.z, l.z); split_bf16(v.w, h.w, l.w);
    *(ushort4*)&hi[i] = h;
    *(ushort4*)&lo[i] = l;
}

// ------- split conv weights: w_out[m][ch][tap] -> wc[tap][m][ch] bf16 -------
__global__ __launch_bounds__(256) void split_wc_kernel(
    const float* __restrict__ w, ushort* __restrict__ hi, ushort* __restrict__ lo) {
    int o = (blockIdx.x*256 + threadIdx.x)*4;   // over 9*320*1024
    int ch = o & 1023;
    int tm = o >> 10; int m = tm % CC; int tap = tm / CC;
    ushort4 h, l;
    float v0 = w[((size_t)m*CTX + ch+0)*9 + tap];
    float v1 = w[((size_t)m*CTX + ch+1)*9 + tap];
    float v2 = w[((size_t)m*CTX + ch+2)*9 + tap];
    float v3 = w[((size_t)m*CTX + ch+3)*9 + tap];
    split_bf16(v0, h.x, l.x); split_bf16(v1, h.y, l.y);
    split_bf16(v2, h.z, l.z); split_bf16(v3, h.w, l.w);
    *(ushort4*)&hi[o] = h;
    *(ushort4*)&lo[o] = l;
}

// ---------------- split w_ctx -> wk hi/lo [m][ch] ----------------
__global__ __launch_bounds__(256) void split_wk_kernel(
    const float* __restrict__ w, ushort* __restrict__ hi, ushort* __restrict__ lo) {
    int i = (blockIdx.x*256 + threadIdx.x)*4;   // over 320*1024
    float4 v = *(const float4*)&w[i];
    ushort4 h, l;
    split_bf16(v.x, h.x, l.x); split_bf16(v.y, h.y, l.y);
    split_bf16(v.z, h.z, l.z); split_bf16(v.w, h.w, l.w);
    *(ushort4*)&hi[i] = h;
    *(ushort4*)&lo[i] = l;
}

// =====================================================================
// MFMA GEMM (bf16x3): out[b][p][m] = sum_k A(pix)[p][k] * W[m][k]
//   NTAPS=9: 3x3 conv over 16x16 map (B-tile reused across taps), K-split.
//   NTAPS=1: plain GEMM (kproj).
// block: 256 threads = 4 waves; block tile P=256 x M=64.
// =====================================================================
template<int NTAPS, bool HASBIAS, int KSPLIT>
__global__ __launch_bounds__(256) void gemm_mfma(
    const ushort* __restrict__ bsrc_hi, const ushort* __restrict__ bsrc_lo,
    const ushort* __restrict__ asrc_hi, const ushort* __restrict__ asrc_lo,
    const float* __restrict__ bias, float* __restrict__ outbuf) {
    int b = blockIdx.x, mt = blockIdx.y, ks = blockIdx.z;
    int tid = threadIdx.x;
    int wave = tid >> 6, lane = tid & 63;
    int l15 = lane & 15, quad = lane >> 4;
    int mbase = mt * 64;

    __shared__ ushort Bs_hi[256*40];
    __shared__ ushort Bs_lo[256*40];
    __shared__ ushort As_hi[64*40];
    __shared__ ushort As_lo[64*40];

    f32x4 acc[4][4];
    #pragma unroll
    for (int sp = 0; sp < 4; ++sp)
        #pragma unroll
        for (int sm = 0; sm < 4; ++sm)
            #pragma unroll
            for (int r = 0; r < 4; ++r) acc[sp][sm][r] = 0.0f;

    const int kbase = ks * (CTX / KSPLIT);
    const int KCH = CTX / KSPLIT / 32;

    // staging coords: thread t -> row = t>>2, 8-elem granule = t&3
    int srow = tid >> 2, sgr = tid & 3;
    size_t bsrc_off = (((size_t)b*CK) << 10) + sgr*8;   // + p*1024 + k0
    int pw = wave * 64;

    #pragma unroll 1
    for (int ci = 0; ci < KCH; ++ci) {
        int k0 = kbase + ci*32;
        __syncthreads();   // all reads of previous Bs/As done
        // stage B-tile: 256 px x 32 ch, hi+lo (4 passes of 64 px)
        #pragma unroll
        for (int pass = 0; pass < 4; ++pass) {
            int p = srow + pass*64;
            size_t so = bsrc_off + ((size_t)p << 10) + k0;
            *(int4*)&Bs_hi[p*40 + sgr*8] = *(const int4*)&bsrc_hi[so];
            *(int4*)&Bs_lo[p*40 + sgr*8] = *(const int4*)&bsrc_lo[so];
        }
        // prefetch tap0 A into regs
        size_t ao = (((size_t)(0*CC + mbase + srow)) << 10) + k0 + sgr*8;
        int4 rAh = *(const int4*)&asrc_hi[ao];
        int4 rAl = *(const int4*)&asrc_lo[ao];

        #pragma unroll 1
        for (int tap = 0; tap < NTAPS; ++tap) {
            if (tap > 0) __syncthreads();  // prev tap's As reads done
            *(int4*)&As_hi[srow*40 + sgr*8] = rAh;
            *(int4*)&As_lo[srow*40 + sgr*8] = rAl;
            if (tap + 1 < NTAPS) {
                size_t an = (((size_t)((tap+1)*CC + mbase + srow)) << 10) + k0 + sgr*8;
                rAh = *(const int4*)&asrc_hi[an];
                rAl = *(const int4*)&asrc_lo[an];
            }
            __syncthreads();

            // weight frags (B-operand): B[k=quad*8+j][n=l15]
            bf16x8 bfh[4], bfl[4];
            #pragma unroll
            for (int sm = 0; sm < 4; ++sm) {
                int off = (sm*16 + l15)*40 + quad*8;
                bfh[sm] = *(const bf16x8*)&As_hi[off];
                bfl[sm] = *(const bf16x8*)&As_lo[off];
            }
            // pixel frags (A-operand): A[m=l15 -> out pixel][k=quad*8+j]
            bf16x8 afh[4], afl[4];
            #pragma unroll
            for (int sp = 0; sp < 4; ++sp) {
                int pout = pw + sp*16 + l15;
                int pin = pout;
                bool val = true;
                if constexpr (NTAPS == 9) {
                    int ty = tap / 3, tx = tap - (tap/3)*3;
                    int iy = (pout >> 4) + ty - 1;
                    int ix = (pout & 15) + tx - 1;
                    val = (iy >= 0) & (iy < 16) & (ix >= 0) & (ix < 16);
                    pin = val ? iy*16 + ix : 0;
                }
                int off = pin*40 + quad*8;
                bf16x8 ah = *(const bf16x8*)&Bs_hi[off];
                bf16x8 al = *(const bf16x8*)&Bs_lo[off];
                if (!val) {
                    #pragma unroll
                    for (int j = 0; j < 8; ++j) { ah[j] = 0; al[j] = 0; }
                }
                afh[sp] = ah; afl[sp] = al;
            }
            #pragma unroll
            for (int sp = 0; sp < 4; ++sp)
                #pragma unroll
                for (int sm = 0; sm < 4; ++sm) {
                    acc[sp][sm] = __builtin_amdgcn_mfma_f32_16x16x32_bf16(
                        afh[sp], bfh[sm], acc[sp][sm], 0, 0, 0);
                    acc[sp][sm] = __builtin_amdgcn_mfma_f32_16x16x32_bf16(
                        afh[sp], bfl[sm], acc[sp][sm], 0, 0, 0);
                    acc[sp][sm] = __builtin_amdgcn_mfma_f32_16x16x32_bf16(
                        afl[sp], bfh[sm], acc[sp][sm], 0, 0, 0);
                }
        }
    }

    // epilogue: D row = out pixel (quad*4+r), col = m (l15)
    size_t outoff = (size_t)ks * N_V + ((size_t)b*CK) * CC;
    #pragma unroll
    for (int sp = 0; sp < 4; ++sp) {
        #pragma unroll
        for (int sm = 0; sm < 4; ++sm) {
            int m = mbase + sm*16 + l15;
            float bv = HASBIAS ? bias[m] : 0.0f;
            #pragma unroll
            for (int r = 0; r < 4; ++r) {
                int p = pw + sp*16 + quad*4 + r;
                outbuf[outoff + (size_t)p*CC + m] = acc[sp][sm][r] + bv;
            }
        }
    }
}

// ---------------- reduce conv partials + bias -> v_t ----------------
__global__ __launch_bounds__(256) void reduce_v_kernel(
    const float* __restrict__ vpart, const float* __restrict__ b_out,
    float* __restrict__ v_t) {
    int i = (blockIdx.x*256 + threadIdx.x)*4;  // over N_V
    float4 a0 = *(const float4*)&vpart[i];
    float4 a1 = *(const float4*)&vpart[(size_t)N_V + i];
    float4 a2 = *(const float4*)&vpart[(size_t)2*N_V + i];
    float4 a3 = *(const float4*)&vpart[(size_t)3*N_V + i];
    int m = i % CC;
    float4 bb = *(const float4*)&b_out[m];
    float4 o;
    o.x = a0.x + a1.x + a2.x + a3.x + bb.x;
    o.y = a0.y + a1.y + a2.y + a3.y + bb.y;
    o.z = a0.z + a1.z + a2.z + a3.z + bb.z;
    o.w = a0.w + a1.w + a2.w + a3.w + bb.w;
    *(float4*)&v_t[i] = o;
}

// ---------------- f32 GEMM core (small GEMMs) ----------------
#define KC 16
#define ASTR 36
#define BSTR 260
#define GEMM_DECL \
    int tid = threadIdx.x; \
    int to = tid >> 5, tp = tid & 31; \
    int ka = tid & 15, ma = (tid >> 4) << 1; \
    __shared__ __align__(16) float As[KC*ASTR]; \
    __shared__ __align__(16) float Bs[KC*BSTR]; \
    float acc[4][8]; \
    _Pragma("unroll") for (int r = 0; r < 4; ++r) \
        _Pragma("unroll") for (int c = 0; c < 8; ++c) acc[r][c] = 0.0f;

#define GEMM_COMPUTE \
    _Pragma("unroll") \
    for (int kk = 0; kk < KC; ++kk) { \
        float a4[4], b8[8]; \
        *(float4*)a4     = *(const float4*)&As[kk*ASTR + (to<<2)]; \
        *(float4*)&b8[0] = *(const float4*)&Bs[kk*BSTR + (tp<<3)]; \
        *(float4*)&b8[4] = *(const float4*)&Bs[kk*BSTR + (tp<<3) + 4]; \
        _Pragma("unroll") for (int r = 0; r < 4; ++r) \
            _Pragma("unroll") for (int c = 0; c < 8; ++c) \
                acc[r][c] += a4[r] * b8[c]; \
    }

// ---------------- q projection: q_t (B,81,320) [s][o] ----------------
__global__ __launch_bounds__(256) void qproj_kernel(
    const float* __restrict__ xg, const float* __restrict__ w_in,
    const float* __restrict__ b_in, const float* __restrict__ ind,
    float* __restrict__ q_t) {
    int b = blockIdx.x, ot = blockIdx.y;
    GEMM_DECL
    int mbase = ot * 32;
    for (int k0 = 0; k0 < CC; k0 += KC) {
        __syncthreads();
        As[ka*ASTR + ma]     = w_in[(size_t)(mbase+ma)  *(CC+2) + k0 + ka];
        As[ka*ASTR + ma + 1] = w_in[(size_t)(mbase+ma+1)*(CC+2) + k0 + ka];
        #pragma unroll
        for (int kk = 0; kk < KC; ++kk) {
            float v = 0.0f;
            if (tid < SS) v = xg[((size_t)b*CC + k0 + kk)*SS + tid];
            Bs[kk*BSTR + tid] = v;
        }
        __syncthreads();
        GEMM_COMPUTE
    }
    int m0 = mbase + (to << 2);
    float i0 = ind[b*2+0], i1 = ind[b*2+1];
    float bias[4];
    #pragma unroll
    for (int r = 0; r < 4; ++r)
        bias[r] = b_in[m0+r] + w_in[(size_t)(m0+r)*(CC+2) + CC]*i0
                             + w_in[(size_t)(m0+r)*(CC+2) + CC+1]*i1;
    #pragma unroll
    for (int c = 0; c < 8; ++c) {
        int n = (tp << 3) + c;
        if (n < SS) {
            float4 o = make_float4(acc[0][c]+bias[0], acc[1][c]+bias[1],
                                   acc[2][c]+bias[2], acc[3][c]+bias[3]);
            *(float4*)&q_t[((size_t)b*SS + n)*CC + m0] = o;
        }
    }
}

// ---------------- sim + softmax -> attn (B,81,256) in d_out ----------------
__global__ __launch_bounds__(256) void simsoft_kernel(
    const float* __restrict__ q_t, const float* __restrict__ k_t,
    float* __restrict__ attn) {
    int b = blockIdx.x, mt = blockIdx.y;  // mt<3
    GEMM_DECL
    int mbase = mt * 32;
    int j0 = tid >> 4;
    for (int k0 = 0; k0 < CC; k0 += KC) {
        __syncthreads();
        int mg = mbase + ma;
        As[ka*ASTR + ma]     = (mg   < SS) ? q_t[((size_t)b*SS + mg  )*CC + k0 + ka] : 0.0f;
        As[ka*ASTR + ma + 1] = (mg+1 < SS) ? q_t[((size_t)b*SS + mg+1)*CC + k0 + ka] : 0.0f;
        #pragma unroll
        for (int i = 0; i < 16; ++i) {
            int j = j0 + (i << 4);
            Bs[ka*BSTR + j] = k_t[((size_t)b*CK + j)*CC + k0 + ka];
        }
        __syncthreads();
        GEMM_COMPUTE
    }
    #pragma unroll
    for (int r = 0; r < 4; ++r) {
        float mx = acc[r][0];
        #pragma unroll
        for (int c = 1; c < 8; ++c) mx = fmaxf(mx, acc[r][c]);
        #pragma unroll
        for (int sh = 16; sh > 0; sh >>= 1) mx = fmaxf(mx, __shfl_xor(mx, sh, 64));
        float ex[8]; float s = 0.0f;
        #pragma unroll
        for (int c = 0; c < 8; ++c) { ex[c] = __expf(acc[r][c] - mx); s += ex[c]; }
        #pragma unroll
        for (int sh = 16; sh > 0; sh >>= 1) s += __shfl_xor(s, sh, 64);
        float inv = 1.0f / s;
        #pragma unroll
        for (int c = 0; c < 8; ++c) acc[r][c] = ex[c] * inv;
    }
    int m0 = mbase + (to << 2);
    #pragma unroll
    for (int r = 0; r < 4; ++r) {
        int m = m0 + r;
        if (m < SS) {
            float* dst = &attn[((size_t)b*SS + m)*CK + (tp << 3)];
            *(float4*)dst       = make_float4(acc[r][0], acc[r][1], acc[r][2], acc[r][3]);
            *(float4*)(dst + 4) = make_float4(acc[r][4], acc[r][5], acc[r][6], acc[r][7]);
        }
    }
}

// ---------------- xo = attn @ v : xo_t (B,81,320) [s][c] ----------------
__global__ __launch_bounds__(256) void xogemm_kernel(
    const float* __restrict__ attn, const float* __restrict__ v_t,
    float* __restrict__ xo_t) {
    int b = blockIdx.x, mt = blockIdx.y, nt = blockIdx.z;  // mt<3, nt<2
    GEMM_DECL
    int mbase = mt * 32, nbase = nt * 256;
    for (int k0 = 0; k0 < CK; k0 += KC) {
        __syncthreads();
        int mg = mbase + ma;
        As[ka*ASTR + ma]     = (mg   < SS) ? attn[((size_t)b*SS + mg  )*CK + k0 + ka] : 0.0f;
        As[ka*ASTR + ma + 1] = (mg+1 < SS) ? attn[((size_t)b*SS + mg+1)*CK + k0 + ka] : 0.0f;
        #pragma unroll
        for (int kk = 0; kk < KC; ++kk) {
            int n = nbase + tid;
            Bs[kk*BSTR + tid] = (n < CC) ? v_t[((size_t)b*CK + k0 + kk)*CC + n] : 0.0f;
        }
        __syncthreads();
        GEMM_COMPUTE
    }
    int m0 = mbase + (to << 2);
    int n0 = nbase + (tp << 3);
    if (n0 + 8 <= CC) {
        #pragma unroll
        for (int r = 0; r < 4; ++r) {
            int m = m0 + r;
            if (m < SS) {
                float* dst = &xo_t[((size_t)b*SS + m)*CC + n0];
                *(float4*)dst       = make_float4(acc[r][0], acc[r][1], acc[r][2], acc[r][3]);
                *(float4*)(dst + 4) = make_float4(acc[r][4], acc[r][5], acc[r][6], acc[r][7]);
            }
        }
    }
}

// ---------------- paste back: out = global_x + masked gather ----------------
__global__ __launch_bounds__(256) void paste_kernel(
    const float* __restrict__ gx, const float* __restrict__ bbox,
    const float* __restrict__ xo_t, float* __restrict__ out) {
    int idx = blockIdx.x * 256 + threadIdx.x;
    int pix = idx & 4095;
    int bc = idx >> 12;
    int c = bc % CC;
    int b = bc / CC;
    int y = pix >> 6, x = pix & 63;
    float g = gx[idx];
    int bx1 = (int)(bbox[b*4+0] * (float)HH);
    int by1 = (int)(bbox[b*4+1] * (float)HH);
    int bx2 = max((int)(bbox[b*4+2] * (float)HH), bx1 + 1);
    int by2 = max((int)(bbox[b*4+3] * (float)HH), by1 + 1);
    float add = 0.0f;
    if (y >= by1 && y < by2 && x >= bx1 && x < bx2) {
        int sy = min(max((y - by1) * ROI / (by2 - by1), 0), ROI - 1);
        int sx = min(max((x - bx1) * ROI / (bx2 - bx1), 0), ROI - 1);
        add = xo_t[((size_t)b*SS + sy*ROI + sx)*CC + c];
    }
    out[idx] = g + add;
}

extern "C" void kernel_launch(void* const* d_in, const int* in_sizes, int n_in,
                              void* d_out, int out_size, void* d_ws, size_t ws_size,
                              hipStream_t stream) {
    const float* global_x = (const float*)d_in[0];
    const float* context  = (const float*)d_in[1];
    const float* indicator= (const float*)d_in[2];
    const float* bbox     = (const float*)d_in[3];
    const float* ln_g     = (const float*)d_in[4];
    const float* ln_b     = (const float*)d_in[5];
    const float* cn_g     = (const float*)d_in[6];
    const float* cn_b     = (const float*)d_in[7];
    const float* w_in     = (const float*)d_in[8];
    const float* b_in     = (const float*)d_in[9];
    const float* w_ctx    = (const float*)d_in[10];
    const float* b_ctx    = (const float*)d_in[11];
    const float* w_out    = (const float*)d_in[12];
    const float* b_out    = (const float*)d_in[13];

    float* ws    = (float*)d_ws;
    float* xg    = ws + OFF_XG;
    ushort* cbfh = (ushort*)(ws + OFF_CBFH);
    ushort* cbfl = (ushort*)(ws + OFF_CBFL);
    ushort* kbfh = (ushort*)(ws + OFF_KBFH);
    ushort* kbfl = (ushort*)(ws + OFF_KBFL);
    ushort* wch  = (ushort*)(ws + OFF_WCH);
    ushort* wcl  = (ushort*)(ws + OFF_WCL);
    ushort* wkh  = (ushort*)(ws + OFF_WKH);
    ushort* wkl  = (ushort*)(ws + OFF_WKL);
    float* vpart = ws + OFF_VPART;
    float* v_t   = ws + OFF_V;
    float* k_t   = ws + OFF_K;
    float* q_t   = ws + OFF_Q;
    float* xo_t  = ws + OFF_XO;

    float* out  = (float*)d_out;                       // (B,320,64,64)
    float* attn = out + (size_t)BB*CC*HH*WW;           // (B,81,256)

    // prep
    roi_gn_kernel   <<<dim3(BB, 32), 256, 0, stream>>>(global_x, bbox, ln_g, ln_b, xg);
    ctx_gn_kernel   <<<dim3(BB, 32), 256, 0, stream>>>(context, cn_g, cn_b, kbfh, kbfl);
    split_ctx_kernel<<<dim3(BB*CK*CTX/1024), 256, 0, stream>>>(context, cbfh, cbfl);
    split_wc_kernel <<<dim3(9*CC*CTX/1024), 256, 0, stream>>>(w_out, wch, wcl);
    split_wk_kernel <<<dim3(CC*CTX/1024), 256, 0, stream>>>(w_ctx, wkh, wkl);
    // projections
    qproj_kernel    <<<dim3(BB, 10), 256, 0, stream>>>(xg, w_in, b_in, indicator, q_t);
    gemm_mfma<1, true, 1><<<dim3(BB, 5, 1), 256, 0, stream>>>(
        kbfh, kbfl, wkh, wkl, b_ctx, k_t);
    gemm_mfma<9, false, 4><<<dim3(BB, 5, 4), 256, 0, stream>>>(
        cbfh, cbfl, wch, wcl, nullptr, vpart);
    reduce_v_kernel <<<dim3(N_V/1024), 256, 0, stream>>>(vpart, b_out, v_t);
    // attention
    simsoft_kernel  <<<dim3(BB, 3),  256, 0, stream>>>(q_t, k_t, attn);
    xogemm_kernel   <<<dim3(BB, 3, 2), 256, 0, stream>>>(attn, v_t, xo_t);
    paste_kernel    <<<dim3((BB*CC*HH*WW)/256), 256, 0, stream>>>(global_x, bbox, xo_t, out);
}